// Round 1
// baseline (1318.911 us; speedup 1.0000x reference)
//
#include <hip/hip_runtime.h>

#define BATCH 4096

// ---------------- ws layout (in floats) ----------------
// slots: [0]=xmax bits, [1..5]=act max bits (stage1..5)  (first 256 floats zeroed)
constexpr int OFF_W1Q = 256;                    // 288
constexpr int OFF_W2Q = OFF_W1Q + 288;          // 18432
constexpr int OFF_W3Q = OFF_W2Q + 18432;        // 1024
constexpr int OFF_W4Q = OFF_W3Q + 1024;         // 2304
constexpr int OFF_W5Q = OFF_W4Q + 2304;         // 1024
constexpr int OFF_WLQ = OFF_W5Q + 1024;         // 640
constexpr int OFF_B1Q = OFF_WLQ + 640;          // 32
constexpr int OFF_B2Q = OFF_B1Q + 32;           // 64
constexpr int OFF_B3Q = OFF_B2Q + 64;           // 16
constexpr int OFF_B4Q = OFF_B3Q + 16;           // 16
constexpr int OFF_B5Q = OFF_B4Q + 16;           // 64
constexpr int OFF_BLQ = OFF_B5Q + 64;           // 10
constexpr int OFF_SKIP1 = 24576;                        // B*64    = 262144
constexpr int OFF_A2    = OFF_SKIP1 + BATCH * 64;       // B*64*64 = 16777216
constexpr int OFF_A1    = OFF_A2 + BATCH * 64 * 64;     // B*32*256= 33554432
// after conv2, a1 region is dead -> reuse for skip2/a3/a4/a5
constexpr int OFF_SKIP2 = OFF_A1;                       // B*64*16 = 4194304
constexpr int OFF_A3    = OFF_SKIP2 + BATCH * 64 * 16;  // B*16*64 = 4194304
constexpr int OFF_A4    = OFF_A3 + BATCH * 16 * 64;     // B*16*16 = 1048576
constexpr int OFF_A5    = OFF_A4 + BATCH * 16 * 16;     // B*64*16 = 4194304
constexpr size_t WS_FLOATS_NEEDED = (size_t)OFF_A1 + (size_t)BATCH * 32 * 256;

// ---------------- helpers ----------------
__device__ __forceinline__ float fq(float x, float scale, float maxv) {
    float q = rintf(x * scale);                 // round-half-even, same as jnp.round
    q = fminf(fmaxf(q, -maxv), maxv);
    return q / scale;                           // divide, matching reference
}

__device__ __forceinline__ float ld_act_scale(const unsigned* slot) {
    return 127.0f / __uint_as_float(*slot);
}

// block-wide max reduce (blockDim.x == 256) then atomicMax into dst (uint-ordered, vals >= 0)
__device__ __forceinline__ void block_max_atomic(float v, unsigned* dst, float* red) {
    int tid = threadIdx.x;
    red[tid] = v;
    __syncthreads();
    for (int s = 128; s > 0; s >>= 1) {
        if (tid < s) red[tid] = fmaxf(red[tid], red[tid + s]);
        __syncthreads();
    }
    if (tid == 0) atomicMax(dst, __float_as_uint(red[0]));
}

// ---------------- weight fake-quant (12 tensors, one block each) ----------------
struct WeightArgs {
    const float* src[12];
    float*       dst[12];
    int          n[12];
    float        maxv[12];
};

__global__ __launch_bounds__(256) void k_weights(WeightArgs a) {
    int t = blockIdx.x;
    const float* s = a.src[t];
    float* d = a.dst[t];
    int n = a.n[t];
    float maxv = a.maxv[t];
    __shared__ float red[256];
    int tid = threadIdx.x;
    float m = 0.f;
    for (int i = tid; i < n; i += 256) m = fmaxf(m, fabsf(s[i]));
    red[tid] = m;
    __syncthreads();
    for (int sft = 128; sft > 0; sft >>= 1) {
        if (tid < sft) red[tid] = fmaxf(red[tid], red[tid + sft]);
        __syncthreads();
    }
    float scale = maxv / red[0];
    for (int i = tid; i < n; i += 256) {
        float q = rintf(s[i] * scale);
        q = fminf(fmaxf(q, -maxv), maxv);
        d[i] = q / scale;
    }
}

// ---------------- global abs-max over x ----------------
__global__ __launch_bounds__(256) void k_absmax(const float* __restrict__ x, int n, unsigned* out) {
    __shared__ float red[256];
    float m = 0.f;
    for (int i = blockIdx.x * 256 + threadIdx.x; i < n; i += gridDim.x * 256)
        m = fmaxf(m, fabsf(x[i]));
    block_max_atomic(m, out, red);
}

// ---------------- skip1 = fq(maxpool(x,5,4,2)) : [B,1,8,8] ----------------
__global__ __launch_bounds__(256) void k_skip1(const float* __restrict__ x,
                                               const unsigned* xmax_bits,
                                               float* __restrict__ skip1) {
    int idx = blockIdx.x * 256 + threadIdx.x;   // B*64
    if (idx >= BATCH * 64) return;
    int b = idx >> 6, p = idx & 63, oh = p >> 3, ow = p & 7;
    const float* xi = x + b * 1024;
    float m = -INFINITY;
    int h0 = oh * 4 - 2, w0 = ow * 4 - 2;
    for (int kh = 0; kh < 5; kh++) {
        int ih = h0 + kh;
        if (ih < 0 || ih >= 32) continue;
        for (int kw = 0; kw < 5; kw++) {
            int iw = w0 + kw;
            if (iw < 0 || iw >= 32) continue;
            m = fmaxf(m, xi[ih * 32 + iw]);
        }
    }
    float sx = ld_act_scale(xmax_bits);
    skip1[idx] = fq(m, sx, 127.f);              // fq(max) == max(fq) (monotone)
}

// ---------------- conv1: 1->32, 3x3, s2 p1, 32x32->16x16, + clipped relu ----------------
__global__ __launch_bounds__(256) void k_conv1(const float* __restrict__ x,
                                               const float* __restrict__ w1q,
                                               const float* __restrict__ b1q,
                                               const unsigned* xmax_bits,
                                               float* __restrict__ a1,
                                               unsigned* actmax) {
    __shared__ float tile[34 * 34];
    __shared__ float red[256];
    int b = blockIdx.x, tid = threadIdx.x;
    float sx = ld_act_scale(xmax_bits);
    for (int i = tid; i < 34 * 34; i += 256) tile[i] = 0.f;
    __syncthreads();
    const float* xi = x + b * 1024;
    for (int i = tid; i < 1024; i += 256) {
        int ih = i >> 5, iw = i & 31;
        tile[(ih + 1) * 34 + (iw + 1)] = fq(xi[i], sx, 127.f);
    }
    __syncthreads();
    int oh = tid >> 4, ow = tid & 15;
    float in[9];
#pragma unroll
    for (int kh = 0; kh < 3; kh++)
#pragma unroll
        for (int kw = 0; kw < 3; kw++)
            in[kh * 3 + kw] = tile[(oh * 2 + kh) * 34 + (ow * 2 + kw)];
    float lmax = 0.f;
    float* o = a1 + (size_t)b * 32 * 256;
    for (int oc = 0; oc < 32; oc++) {
        float acc = b1q[oc];
#pragma unroll
        for (int k = 0; k < 9; k++) acc += in[k] * w1q[oc * 9 + k];
        float v = fminf(fmaxf(acc, 0.f), 10.f);
        o[oc * 256 + tid] = v;
        lmax = fmaxf(lmax, v);
    }
    block_max_atomic(lmax, actmax, red);
}

// ---------------- conv2: 32->64, 3x3, s2 p1, 16x16->8x8, +bias +skip1, clip ----------------
__global__ __launch_bounds__(256) void k_conv2(const float* __restrict__ a1,
                                               const float* __restrict__ w2q,
                                               const float* __restrict__ b2q,
                                               const float* __restrict__ skip1,
                                               const unsigned* m1bits,
                                               float* __restrict__ a2,
                                               unsigned* actmax) {
    __shared__ float tile[32 * 18 * 18];   // 41.5 KB, zero-padded
    __shared__ float red[256];
    int b = blockIdx.x, tid = threadIdx.x;
    float s1 = ld_act_scale(m1bits);
    for (int i = tid; i < 32 * 18 * 18; i += 256) tile[i] = 0.f;
    __syncthreads();
    const float* ai = a1 + (size_t)b * 8192;
    for (int i = tid; i < 8192; i += 256) {
        int ic = i >> 8, p = i & 255, ih = p >> 4, iw = p & 15;
        tile[ic * 324 + (ih + 1) * 18 + (iw + 1)] = fq(ai[i], s1, 127.f);
    }
    __syncthreads();
    int p = tid & 63, grp = tid >> 6;
    int oh = p >> 3, ow = p & 7;
    float sk = skip1[b * 64 + p];
    float lmax = 0.f;
    float* o = a2 + (size_t)b * 64 * 64;
    for (int j = 0; j < 16; j++) {
        int oc = grp * 16 + j;
        float acc = b2q[oc];
        const float* w = w2q + oc * 288;
        for (int ic = 0; ic < 32; ic++) {
            const float* tin = tile + ic * 324 + (oh * 2) * 18 + (ow * 2);
            const float* wc = w + ic * 9;
#pragma unroll
            for (int kh = 0; kh < 3; kh++)
#pragma unroll
                for (int kw = 0; kw < 3; kw++)
                    acc += tin[kh * 18 + kw] * wc[kh * 3 + kw];
        }
        acc += sk;
        float v = fminf(fmaxf(acc, 0.f), 10.f);
        o[oc * 64 + p] = v;
        lmax = fmaxf(lmax, v);
    }
    block_max_atomic(lmax, actmax, red);
}

// ---------------- skip2 = fq(maxpool(a2,3,2,1)) : [B,64,4,4] ----------------
__global__ __launch_bounds__(256) void k_skip2(const float* __restrict__ a2,
                                               const unsigned* m2bits,
                                               float* __restrict__ skip2) {
    int idx = blockIdx.x * 256 + threadIdx.x;   // B*64*16
    if (idx >= BATCH * 1024) return;
    int b = idx >> 10, r = idx & 1023, c = r >> 4, p = r & 15;
    int oh = p >> 2, ow = p & 3;
    const float* ai = a2 + (size_t)b * 4096 + c * 64;
    float m = -INFINITY;
    for (int kh = 0; kh < 3; kh++) {
        int ih = oh * 2 - 1 + kh;
        if (ih < 0 || ih >= 8) continue;
        for (int kw = 0; kw < 3; kw++) {
            int iw = ow * 2 - 1 + kw;
            if (iw < 0 || iw >= 8) continue;
            m = fmaxf(m, ai[ih * 8 + iw]);
        }
    }
    float s2 = ld_act_scale(m2bits);
    skip2[idx] = fq(m, s2, 127.f);
}

// ---------------- conv3: 1x1, 64->16 on 8x8, clip ----------------
__global__ __launch_bounds__(256) void k_conv3(const float* __restrict__ a2,
                                               const float* __restrict__ w3q,
                                               const float* __restrict__ b3q,
                                               const unsigned* m2bits,
                                               float* __restrict__ a3,
                                               unsigned* actmax) {
    __shared__ float tin[64 * 64];
    __shared__ float red[256];
    int b = blockIdx.x, tid = threadIdx.x;
    float s2 = ld_act_scale(m2bits);
    const float* ai = a2 + (size_t)b * 4096;
    for (int i = tid; i < 4096; i += 256) tin[i] = fq(ai[i], s2, 127.f);
    __syncthreads();
    int p = tid & 63, grp = tid >> 6;
    float lmax = 0.f;
    float* o = a3 + (size_t)b * 1024;
    for (int j = 0; j < 4; j++) {
        int oc = grp * 4 + j;
        float acc = b3q[oc];
        const float* w = w3q + oc * 64;
        for (int ic = 0; ic < 64; ic++) acc += tin[ic * 64 + p] * w[ic];
        float v = fminf(fmaxf(acc, 0.f), 10.f);
        o[oc * 64 + p] = v;
        lmax = fmaxf(lmax, v);
    }
    block_max_atomic(lmax, actmax, red);
}

// ---------------- conv4: 3x3, s2 p1, 16->16, 8x8->4x4, clip ----------------
__global__ __launch_bounds__(256) void k_conv4(const float* __restrict__ a3,
                                               const float* __restrict__ w4q,
                                               const float* __restrict__ b4q,
                                               const unsigned* m3bits,
                                               float* __restrict__ a4,
                                               unsigned* actmax) {
    __shared__ float tile[16 * 10 * 10];
    __shared__ float red[256];
    int b = blockIdx.x, tid = threadIdx.x;
    float s3 = ld_act_scale(m3bits);
    for (int i = tid; i < 1600; i += 256) tile[i] = 0.f;
    __syncthreads();
    const float* ai = a3 + (size_t)b * 1024;
    for (int i = tid; i < 1024; i += 256) {
        int ic = i >> 6, p = i & 63, ih = p >> 3, iw = p & 7;
        tile[ic * 100 + (ih + 1) * 10 + (iw + 1)] = fq(ai[i], s3, 127.f);
    }
    __syncthreads();
    int oc = tid >> 4, p = tid & 15, oh = p >> 2, ow = p & 3;
    float acc = b4q[oc];
    const float* w = w4q + oc * 144;
    for (int ic = 0; ic < 16; ic++) {
        const float* tin = tile + ic * 100 + (oh * 2) * 10 + (ow * 2);
        const float* wc = w + ic * 9;
#pragma unroll
        for (int kh = 0; kh < 3; kh++)
#pragma unroll
            for (int kw = 0; kw < 3; kw++)
                acc += tin[kh * 10 + kw] * wc[kh * 3 + kw];
    }
    float v = fminf(fmaxf(acc, 0.f), 10.f);
    a4[(size_t)b * 256 + tid] = v;              // [B,16,4,4], tid = oc*16+p
    block_max_atomic(v, actmax, red);
}

// ---------------- conv5: 1x1, 16->64 on 4x4, +skip2, clip ----------------
__global__ __launch_bounds__(256) void k_conv5(const float* __restrict__ a4,
                                               const float* __restrict__ w5q,
                                               const float* __restrict__ b5q,
                                               const float* __restrict__ skip2,
                                               const unsigned* m4bits,
                                               float* __restrict__ a5,
                                               unsigned* actmax) {
    __shared__ float tin[256];
    __shared__ float red[256];
    int b = blockIdx.x, tid = threadIdx.x;
    float s4 = ld_act_scale(m4bits);
    const float* ai = a4 + (size_t)b * 256;
    tin[tid] = fq(ai[tid], s4, 127.f);
    __syncthreads();
    int p = tid & 15, ocb = tid >> 4;   // ocb 0..15 -> oc = ocb*4+j
    float lmax = 0.f;
    float* o = a5 + (size_t)b * 1024;
    for (int j = 0; j < 4; j++) {
        int oc = ocb * 4 + j;
        float acc = b5q[oc];
        const float* w = w5q + oc * 16;
#pragma unroll
        for (int ic = 0; ic < 16; ic++) acc += tin[ic * 16 + p] * w[ic];
        acc += skip2[(size_t)b * 1024 + oc * 16 + p];
        float v = fminf(fmaxf(acc, 0.f), 10.f);
        o[oc * 16 + p] = v;
        lmax = fmaxf(lmax, v);
    }
    block_max_atomic(lmax, actmax, red);
}

// ---------------- head: fq(a5) -> mean(4x4) -> linear ----------------
__global__ __launch_bounds__(64) void k_head(const float* __restrict__ a5,
                                             const unsigned* m5bits,
                                             const float* __restrict__ wlq,
                                             const float* __restrict__ blq,
                                             float* __restrict__ out) {
    __shared__ float h[64];
    int b = blockIdx.x, c = threadIdx.x;
    float s5 = ld_act_scale(m5bits);
    const float* ai = a5 + (size_t)b * 1024 + c * 16;
    float sum = 0.f;
#pragma unroll
    for (int p = 0; p < 16; p++) sum += fq(ai[p], s5, 127.f);
    h[c] = sum * (1.f / 16.f);
    __syncthreads();
    if (c < 10) {
        float acc = blq[c];
        const float* w = wlq + c * 64;
        for (int ic = 0; ic < 64; ic++) acc += h[ic] * w[ic];
        out[(size_t)b * 10 + c] = acc;
    }
}

// ---------------- launch ----------------
extern "C" void kernel_launch(void* const* d_in, const int* in_sizes, int n_in,
                              void* d_out, int out_size, void* d_ws, size_t ws_size,
                              hipStream_t stream) {
    const float* x  = (const float*)d_in[0];
    const float* w1 = (const float*)d_in[1];
    const float* b1 = (const float*)d_in[2];
    const float* w2 = (const float*)d_in[3];
    const float* b2 = (const float*)d_in[4];
    const float* w3 = (const float*)d_in[5];
    const float* b3 = (const float*)d_in[6];
    const float* w4 = (const float*)d_in[7];
    const float* b4 = (const float*)d_in[8];
    const float* w5 = (const float*)d_in[9];
    const float* b5 = (const float*)d_in[10];
    const float* wl = (const float*)d_in[11];
    const float* bl = (const float*)d_in[12];

    if (ws_size < WS_FLOATS_NEEDED * sizeof(float)) return;  // ws too small: fail cleanly

    float* ws = (float*)d_ws;
    unsigned* slots = (unsigned*)d_ws;   // [0]=xmax, [1..5]=act maxes

    hipMemsetAsync(d_ws, 0, 1024, stream);   // zero the slot region (capturable)

    WeightArgs wa;
    const float* srcs[12] = {w1, w2, w3, w4, w5, wl, b1, b2, b3, b4, b5, bl};
    const int    ns[12]   = {288, 18432, 1024, 2304, 1024, 640, 32, 64, 16, 16, 64, 10};
    const int    offs[12] = {OFF_W1Q, OFF_W2Q, OFF_W3Q, OFF_W4Q, OFF_W5Q, OFF_WLQ,
                             OFF_B1Q, OFF_B2Q, OFF_B3Q, OFF_B4Q, OFF_B5Q, OFF_BLQ};
    const float  mv[12]   = {127.f, 127.f, 127.f, 127.f, 127.f, 127.f,
                             32767.f, 32767.f, 32767.f, 32767.f, 32767.f, 32767.f};
    for (int i = 0; i < 12; i++) {
        wa.src[i] = srcs[i];
        wa.dst[i] = ws + offs[i];
        wa.n[i] = ns[i];
        wa.maxv[i] = mv[i];
    }
    k_weights<<<12, 256, 0, stream>>>(wa);

    k_absmax<<<1024, 256, 0, stream>>>(x, BATCH * 1024, slots + 0);
    k_skip1<<<BATCH * 64 / 256, 256, 0, stream>>>(x, slots + 0, ws + OFF_SKIP1);
    k_conv1<<<BATCH, 256, 0, stream>>>(x, ws + OFF_W1Q, ws + OFF_B1Q, slots + 0,
                                       ws + OFF_A1, slots + 1);
    k_conv2<<<BATCH, 256, 0, stream>>>(ws + OFF_A1, ws + OFF_W2Q, ws + OFF_B2Q,
                                       ws + OFF_SKIP1, slots + 1, ws + OFF_A2, slots + 2);
    k_skip2<<<BATCH * 1024 / 256, 256, 0, stream>>>(ws + OFF_A2, slots + 2, ws + OFF_SKIP2);
    k_conv3<<<BATCH, 256, 0, stream>>>(ws + OFF_A2, ws + OFF_W3Q, ws + OFF_B3Q, slots + 2,
                                       ws + OFF_A3, slots + 3);
    k_conv4<<<BATCH, 256, 0, stream>>>(ws + OFF_A3, ws + OFF_W4Q, ws + OFF_B4Q, slots + 3,
                                       ws + OFF_A4, slots + 4);
    k_conv5<<<BATCH, 256, 0, stream>>>(ws + OFF_A4, ws + OFF_W5Q, ws + OFF_B5Q,
                                       ws + OFF_SKIP2, slots + 4, ws + OFF_A5, slots + 5);
    k_head<<<BATCH, 64, 0, stream>>>(ws + OFF_A5, slots + 5, ws + OFF_WLQ, ws + OFF_BLQ,
                                     (float*)d_out);
}

// Round 3
// 538.210 us; speedup vs baseline: 2.4506x; 2.4506x over previous
//
#include <hip/hip_runtime.h>

#define BATCH 4096

// ---------------- ws layout (in floats) ----------------
// slots: [0]=xmax bits, [1..5]=act max bits (stage1..5)  (first 256 floats zeroed)
constexpr int OFF_W1Q = 256;                    // 288
constexpr int OFF_W2Q = OFF_W1Q + 288;          // 18432
constexpr int OFF_W3Q = OFF_W2Q + 18432;        // 1024
constexpr int OFF_W4Q = OFF_W3Q + 1024;         // 2304
constexpr int OFF_W5Q = OFF_W4Q + 2304;         // 1024
constexpr int OFF_WLQ = OFF_W5Q + 1024;         // 640
constexpr int OFF_B1Q = OFF_WLQ + 640;          // 32
constexpr int OFF_B2Q = OFF_B1Q + 32;           // 64
constexpr int OFF_B3Q = OFF_B2Q + 64;           // 16
constexpr int OFF_B4Q = OFF_B3Q + 16;           // 16
constexpr int OFF_B5Q = OFF_B4Q + 16;           // 64
constexpr int OFF_BLQ = OFF_B5Q + 64;           // 10
constexpr int OFF_SKIP1 = 24576;                        // B*64    = 262144
constexpr int OFF_A2    = OFF_SKIP1 + BATCH * 64;       // B*64*64 = 16777216
constexpr int OFF_A1    = OFF_A2 + BATCH * 64 * 64;     // B*32*256= 33554432
// after conv2, a1 region is dead -> reuse for skip2/a3/a4/a5
constexpr int OFF_SKIP2 = OFF_A1;                       // B*64*16 = 4194304
constexpr int OFF_A3    = OFF_SKIP2 + BATCH * 64 * 16;  // B*16*64 = 4194304
constexpr int OFF_A4    = OFF_A3 + BATCH * 16 * 64;     // B*16*16 = 1048576
constexpr int OFF_A5    = OFF_A4 + BATCH * 16 * 16;     // B*64*16 = 4194304
// w2 reordered [9][32][64] lives after a1 (must persist while a1 is alive)
constexpr size_t OFF_W2R = (size_t)OFF_A1 + (size_t)BATCH * 32 * 256;
constexpr size_t WS_FLOATS_NEEDED = OFF_W2R + 18432 + 64;

// ---------------- helpers ----------------
__device__ __forceinline__ float fq(float x, float scale, float maxv) {
    float q = rintf(x * scale);                 // round-half-even, same as jnp.round
    q = fminf(fmaxf(q, -maxv), maxv);
    return q / scale;                           // divide, matching reference
}

__device__ __forceinline__ float ld_act_scale(const unsigned* slot) {
    return 127.0f / __uint_as_float(*slot);
}

// block-wide max reduce (blockDim.x == 256) then atomicMax into dst (uint-ordered, vals >= 0)
__device__ __forceinline__ void block_max_atomic(float v, unsigned* dst, float* red) {
    int tid = threadIdx.x;
    red[tid] = v;
    __syncthreads();
    for (int s = 128; s > 0; s >>= 1) {
        if (tid < s) red[tid] = fmaxf(red[tid], red[tid + s]);
        __syncthreads();
    }
    if (tid == 0) atomicMax(dst, __float_as_uint(red[0]));
}

// ---------------- weight fake-quant (12 tensors, one block each) ----------------
struct WeightArgs {
    const float* src[12];
    float*       dst[12];
    int          n[12];
    float        maxv[12];
};

__global__ __launch_bounds__(256) void k_weights(WeightArgs a) {
    int t = blockIdx.x;
    const float* s = a.src[t];
    float* d = a.dst[t];
    int n = a.n[t];
    float maxv = a.maxv[t];
    __shared__ float red[256];
    int tid = threadIdx.x;
    float m = 0.f;
    for (int i = tid; i < n; i += 256) m = fmaxf(m, fabsf(s[i]));
    red[tid] = m;
    __syncthreads();
    for (int sft = 128; sft > 0; sft >>= 1) {
        if (tid < sft) red[tid] = fmaxf(red[tid], red[tid + sft]);
        __syncthreads();
    }
    float scale = maxv / red[0];
    for (int i = tid; i < n; i += 256) {
        float q = rintf(s[i] * scale);
        q = fminf(fmaxf(q, -maxv), maxv);
        d[i] = q / scale;
    }
}

// w2q [64][32][9] -> w2r [9][32][64]
__global__ __launch_bounds__(256) void k_reorder_w2(const float* __restrict__ w2q,
                                                    float* __restrict__ w2r) {
    for (int i = threadIdx.x + blockIdx.x * 256; i < 18432; i += 256 * gridDim.x) {
        int oc = i / 288, r = i % 288, ic = r / 9, t = r % 9;
        w2r[(t * 32 + ic) * 64 + oc] = w2q[i];
    }
}

// ---------------- global abs-max over x (float4-vectorized) ----------------
__global__ __launch_bounds__(256) void k_absmax(const float4* __restrict__ x, int n4,
                                                unsigned* out) {
    __shared__ float red[256];
    float m = 0.f;
    for (int i = blockIdx.x * 256 + threadIdx.x; i < n4; i += gridDim.x * 256) {
        float4 v = x[i];
        m = fmaxf(m, fmaxf(fmaxf(fabsf(v.x), fabsf(v.y)), fmaxf(fabsf(v.z), fabsf(v.w))));
    }
    block_max_atomic(m, out, red);
}

// ---------------- conv1: 1->32, 3x3, s2 p1, 32x32->16x16, + clipped relu; also skip1 ----------------
__global__ __launch_bounds__(256) void k_conv1(const float* __restrict__ x,
                                               const float* __restrict__ w1q,
                                               const float* __restrict__ b1q,
                                               const unsigned* xmax_bits,
                                               float* __restrict__ a1,
                                               float* __restrict__ skip1,
                                               unsigned* actmax) {
    __shared__ float tile[34 * 34];
    __shared__ float red[256];
    int b = blockIdx.x, tid = threadIdx.x;
    float sx = ld_act_scale(xmax_bits);
    for (int i = tid; i < 34 * 34; i += 256) tile[i] = 0.f;
    __syncthreads();
    const float* xi = x + b * 1024;
    for (int i = tid; i < 1024; i += 256) {
        int ih = i >> 5, iw = i & 31;
        tile[(ih + 1) * 34 + (iw + 1)] = fq(xi[i], sx, 127.f);
    }
    __syncthreads();
    // skip1 = fq(maxpool(x,5,4,2)) computed from raw x (global; image is L1-hot)
    if (tid < 64) {
        int soh = tid >> 3, sow = tid & 7;
        float m = -INFINITY;
        int h0 = soh * 4 - 2, w0 = sow * 4 - 2;
        for (int kh = 0; kh < 5; kh++) {
            int ih = h0 + kh;
            if (ih < 0 || ih >= 32) continue;
            for (int kw = 0; kw < 5; kw++) {
                int iw = w0 + kw;
                if (iw < 0 || iw >= 32) continue;
                m = fmaxf(m, xi[ih * 32 + iw]);
            }
        }
        skip1[b * 64 + tid] = fq(m, sx, 127.f);  // fq monotone: fq(max)==max(fq)
    }
    int oh = tid >> 4, ow = tid & 15;
    float in[9];
#pragma unroll
    for (int kh = 0; kh < 3; kh++)
#pragma unroll
        for (int kw = 0; kw < 3; kw++)
            in[kh * 3 + kw] = tile[(oh * 2 + kh) * 34 + (ow * 2 + kw)];
    float lmax = 0.f;
    float* o = a1 + (size_t)b * 32 * 256;
    for (int oc = 0; oc < 32; oc++) {
        float acc = b1q[oc];
#pragma unroll
        for (int k = 0; k < 9; k++) acc += in[k] * w1q[oc * 9 + k];
        float v = fminf(fmaxf(acc, 0.f), 10.f);
        o[oc * 256 + tid] = v;
        lmax = fmaxf(lmax, v);
    }
    block_max_atomic(lmax, actmax, red);
}

// ---------------- conv2: 32->64, 3x3, s2 p1, 16x16->8x8, +bias +skip1, clip ----------------
// register-blocked: inputs hoisted per-ic, weights via wave-uniform loads from [9][32][64]
__global__ __launch_bounds__(256) void k_conv2(const float* __restrict__ a1,
                                               const float* __restrict__ w2r,
                                               const float* __restrict__ b2q,
                                               const float* __restrict__ skip1,
                                               const unsigned* m1bits,
                                               float* __restrict__ a2,
                                               unsigned* actmax) {
    __shared__ float tile[32 * 18 * 18];   // 41.5 KB, zero-padded
    __shared__ float red[256];
    int b = blockIdx.x, tid = threadIdx.x;
    float s1 = ld_act_scale(m1bits);
    for (int i = tid; i < 32 * 324; i += 256) tile[i] = 0.f;
    __syncthreads();
    const float* ai = a1 + (size_t)b * 8192;
    for (int i = tid; i < 8192; i += 256) {
        int ic = i >> 8, p = i & 255, ih = p >> 4, iw = p & 15;
        tile[ic * 324 + (ih + 1) * 18 + (iw + 1)] = fq(ai[i], s1, 127.f);
    }
    __syncthreads();
    int p = tid & 63;
    int grp = __builtin_amdgcn_readfirstlane(tid >> 6);   // wave-uniform -> scalar weight loads
    int oh = p >> 3, ow = p & 7;
    const float* wbase = w2r + grp * 16;
    const float* bb = b2q + grp * 16;
    float acc[16];
#pragma unroll
    for (int j = 0; j < 16; ++j) acc[j] = bb[j];
    const float* tbase = tile + (oh * 2) * 18 + (ow * 2);
#pragma unroll 2
    for (int ic = 0; ic < 32; ++ic) {
        float in[9];
#pragma unroll
        for (int kh = 0; kh < 3; ++kh)
#pragma unroll
            for (int kw = 0; kw < 3; ++kw)
                in[kh * 3 + kw] = tbase[ic * 324 + kh * 18 + kw];
#pragma unroll
        for (int t = 0; t < 9; ++t) {
            const float* wp = wbase + (t * 32 + ic) * 64;   // uniform address
#pragma unroll
            for (int j = 0; j < 16; ++j)
                acc[j] = fmaf(in[t], wp[j], acc[j]);
        }
    }
    float sk = skip1[b * 64 + p];
    float lmax = 0.f;
    float* o = a2 + (size_t)b * 4096;
#pragma unroll
    for (int j = 0; j < 16; ++j) {
        float v = fminf(fmaxf(acc[j] + sk, 0.f), 10.f);
        o[(grp * 16 + j) * 64 + p] = v;
        lmax = fmaxf(lmax, v);
    }
    block_max_atomic(lmax, actmax, red);
}

// ---------------- conv3: 1x1, 64->16 on 8x8, clip; also skip2 = maxpool(fq(a2),3,2,1) ----------------
__global__ __launch_bounds__(256) void k_conv3(const float* __restrict__ a2,
                                               const float* __restrict__ w3q,
                                               const float* __restrict__ b3q,
                                               const unsigned* m2bits,
                                               float* __restrict__ a3,
                                               float* __restrict__ skip2,
                                               unsigned* actmax) {
    __shared__ float tin[64 * 64];
    __shared__ float red[256];
    int b = blockIdx.x, tid = threadIdx.x;
    float s2 = ld_act_scale(m2bits);
    const float* ai = a2 + (size_t)b * 4096;
    for (int i = tid; i < 4096; i += 256) tin[i] = fq(ai[i], s2, 127.f);
    __syncthreads();
    // skip2: fq'd values already in tin; pool with bounds (monotone fq)
    float* sko = skip2 + (size_t)b * 1024;
#pragma unroll
    for (int r = 0; r < 4; ++r) {
        int idx = tid * 4 + r;            // 0..1023
        int c = idx >> 4, pp = idx & 15, soh = pp >> 2, sow = pp & 3;
        float m = -INFINITY;
        for (int kh = 0; kh < 3; kh++) {
            int ih = soh * 2 - 1 + kh;
            if (ih < 0 || ih >= 8) continue;
            for (int kw = 0; kw < 3; kw++) {
                int iw = sow * 2 - 1 + kw;
                if (iw < 0 || iw >= 8) continue;
                m = fmaxf(m, tin[c * 64 + ih * 8 + iw]);
            }
        }
        sko[idx] = m;
    }
    int p = tid & 63;
    int grp = __builtin_amdgcn_readfirstlane(tid >> 6);
    float acc[4];
#pragma unroll
    for (int j = 0; j < 4; ++j) acc[j] = b3q[grp * 4 + j];
    for (int ic = 0; ic < 64; ++ic) {
        float v = tin[ic * 64 + p];
#pragma unroll
        for (int j = 0; j < 4; ++j)
            acc[j] = fmaf(v, w3q[(grp * 4 + j) * 64 + ic], acc[j]);
    }
    float lmax = 0.f;
    float* o = a3 + (size_t)b * 1024;
#pragma unroll
    for (int j = 0; j < 4; ++j) {
        float v = fminf(fmaxf(acc[j], 0.f), 10.f);
        o[(grp * 4 + j) * 64 + p] = v;
        lmax = fmaxf(lmax, v);
    }
    block_max_atomic(lmax, actmax, red);
}

// ---------------- conv4: 3x3, s2 p1, 16->16, 8x8->4x4, clip ----------------
__global__ __launch_bounds__(256) void k_conv4(const float* __restrict__ a3,
                                               const float* __restrict__ w4q,
                                               const float* __restrict__ b4q,
                                               const unsigned* m3bits,
                                               float* __restrict__ a4,
                                               unsigned* actmax) {
    __shared__ float tile[16 * 10 * 10];
    __shared__ float red[256];
    int b = blockIdx.x, tid = threadIdx.x;
    float s3 = ld_act_scale(m3bits);
    for (int i = tid; i < 1600; i += 256) tile[i] = 0.f;
    __syncthreads();
    const float* ai = a3 + (size_t)b * 1024;
    for (int i = tid; i < 1024; i += 256) {
        int ic = i >> 6, p = i & 63, ih = p >> 3, iw = p & 7;
        tile[ic * 100 + (ih + 1) * 10 + (iw + 1)] = fq(ai[i], s3, 127.f);
    }
    __syncthreads();
    int oc = tid >> 4, p = tid & 15, oh = p >> 2, ow = p & 3;
    float acc = b4q[oc];
    const float* w = w4q + oc * 144;
    for (int ic = 0; ic < 16; ic++) {
        const float* tin = tile + ic * 100 + (oh * 2) * 10 + (ow * 2);
        const float* wc = w + ic * 9;
#pragma unroll
        for (int kh = 0; kh < 3; kh++)
#pragma unroll
            for (int kw = 0; kw < 3; kw++)
                acc += tin[kh * 10 + kw] * wc[kh * 3 + kw];
    }
    float v = fminf(fmaxf(acc, 0.f), 10.f);
    a4[(size_t)b * 256 + tid] = v;              // [B,16,4,4], tid = oc*16+p
    block_max_atomic(v, actmax, red);
}

// ---------------- conv5: 1x1, 16->64 on 4x4, +skip2, clip ----------------
__global__ __launch_bounds__(256) void k_conv5(const float* __restrict__ a4,
                                               const float* __restrict__ w5q,
                                               const float* __restrict__ b5q,
                                               const float* __restrict__ skip2,
                                               const unsigned* m4bits,
                                               float* __restrict__ a5,
                                               unsigned* actmax) {
    __shared__ float tin[256];
    __shared__ float red[256];
    int b = blockIdx.x, tid = threadIdx.x;
    float s4 = ld_act_scale(m4bits);
    const float* ai = a4 + (size_t)b * 256;
    tin[tid] = fq(ai[tid], s4, 127.f);
    __syncthreads();
    int p = tid & 15, ocb = tid >> 4;   // ocb 0..15 -> oc = ocb*4+j
    float lmax = 0.f;
    float* o = a5 + (size_t)b * 1024;
    for (int j = 0; j < 4; j++) {
        int oc = ocb * 4 + j;
        float acc = b5q[oc];
        const float* w = w5q + oc * 16;
#pragma unroll
        for (int ic = 0; ic < 16; ic++) acc += tin[ic * 16 + p] * w[ic];
        acc += skip2[(size_t)b * 1024 + oc * 16 + p];
        float v = fminf(fmaxf(acc, 0.f), 10.f);
        o[oc * 16 + p] = v;
        lmax = fmaxf(lmax, v);
    }
    block_max_atomic(lmax, actmax, red);
}

// ---------------- head: fq(a5) -> mean(4x4) -> linear ----------------
__global__ __launch_bounds__(64) void k_head(const float* __restrict__ a5,
                                             const unsigned* m5bits,
                                             const float* __restrict__ wlq,
                                             const float* __restrict__ blq,
                                             float* __restrict__ out) {
    __shared__ float h[64];
    int b = blockIdx.x, c = threadIdx.x;
    float s5 = ld_act_scale(m5bits);
    const float* ai = a5 + (size_t)b * 1024 + c * 16;
    float sum = 0.f;
#pragma unroll
    for (int p = 0; p < 16; p++) sum += fq(ai[p], s5, 127.f);
    h[c] = sum * (1.f / 16.f);
    __syncthreads();
    if (c < 10) {
        float acc = blq[c];
        const float* w = wlq + c * 64;
        for (int ic = 0; ic < 64; ic++) acc += h[ic] * w[ic];
        out[(size_t)b * 10 + c] = acc;
    }
}

// ---------------- launch ----------------
extern "C" void kernel_launch(void* const* d_in, const int* in_sizes, int n_in,
                              void* d_out, int out_size, void* d_ws, size_t ws_size,
                              hipStream_t stream) {
    const float* x  = (const float*)d_in[0];
    const float* w1 = (const float*)d_in[1];
    const float* b1 = (const float*)d_in[2];
    const float* w2 = (const float*)d_in[3];
    const float* b2 = (const float*)d_in[4];
    const float* w3 = (const float*)d_in[5];
    const float* b3 = (const float*)d_in[6];
    const float* w4 = (const float*)d_in[7];
    const float* b4 = (const float*)d_in[8];
    const float* w5 = (const float*)d_in[9];
    const float* b5 = (const float*)d_in[10];
    const float* wl = (const float*)d_in[11];
    const float* bl = (const float*)d_in[12];

    if (ws_size < WS_FLOATS_NEEDED * sizeof(float)) return;  // ws too small: fail cleanly

    float* ws = (float*)d_ws;
    unsigned* slots = (unsigned*)d_ws;   // [0]=xmax, [1..5]=act maxes

    hipMemsetAsync(d_ws, 0, 1024, stream);   // zero the slot region (capturable)

    WeightArgs wa;
    const float* srcs[12] = {w1, w2, w3, w4, w5, wl, b1, b2, b3, b4, b5, bl};
    const int    ns[12]   = {288, 18432, 1024, 2304, 1024, 640, 32, 64, 16, 16, 64, 10};
    const int    offs[12] = {OFF_W1Q, OFF_W2Q, OFF_W3Q, OFF_W4Q, OFF_W5Q, OFF_WLQ,
                             OFF_B1Q, OFF_B2Q, OFF_B3Q, OFF_B4Q, OFF_B5Q, OFF_BLQ};
    const float  mv[12]   = {127.f, 127.f, 127.f, 127.f, 127.f, 127.f,
                             32767.f, 32767.f, 32767.f, 32767.f, 32767.f, 32767.f};
    for (int i = 0; i < 12; i++) {
        wa.src[i] = srcs[i];
        wa.dst[i] = ws + offs[i];
        wa.n[i] = ns[i];
        wa.maxv[i] = mv[i];
    }
    k_weights<<<12, 256, 0, stream>>>(wa);
    k_reorder_w2<<<8, 256, 0, stream>>>(ws + OFF_W2Q, ws + OFF_W2R);

    k_absmax<<<512, 256, 0, stream>>>((const float4*)x, BATCH * 1024 / 4, slots + 0);
    k_conv1<<<BATCH, 256, 0, stream>>>(x, ws + OFF_W1Q, ws + OFF_B1Q, slots + 0,
                                       ws + OFF_A1, ws + OFF_SKIP1, slots + 1);
    k_conv2<<<BATCH, 256, 0, stream>>>(ws + OFF_A1, ws + OFF_W2R, ws + OFF_B2Q,
                                       ws + OFF_SKIP1, slots + 1, ws + OFF_A2, slots + 2);
    k_conv3<<<BATCH, 256, 0, stream>>>(ws + OFF_A2, ws + OFF_W3Q, ws + OFF_B3Q, slots + 2,
                                       ws + OFF_A3, ws + OFF_SKIP2, slots + 3);
    k_conv4<<<BATCH, 256, 0, stream>>>(ws + OFF_A3, ws + OFF_W4Q, ws + OFF_B4Q, slots + 3,
                                       ws + OFF_A4, slots + 4);
    k_conv5<<<BATCH, 256, 0, stream>>>(ws + OFF_A4, ws + OFF_W5Q, ws + OFF_B5Q,
                                       ws + OFF_SKIP2, slots + 4, ws + OFF_A5, slots + 5);
    k_head<<<BATCH, 64, 0, stream>>>(ws + OFF_A5, slots + 5, ws + OFF_WLQ, ws + OFF_BLQ,
                                     (float*)d_out);
}

// Round 4
// 415.439 us; speedup vs baseline: 3.1747x; 1.2955x over previous
//
#include <hip/hip_runtime.h>

#define BATCH 4096

typedef __attribute__((ext_vector_type(8))) short bf16x8;
typedef __attribute__((ext_vector_type(4))) float f32x4;
typedef __attribute__((ext_vector_type(4))) short short4v;

// ---------------- ws layout (in floats) ----------------
// slots: [0]=xmax bits, [1..5]=act max bits (stage1..5), [6]=inv_sw2 (float)
constexpr int OFF_W1Q = 256;                    // 288
constexpr int OFF_W2Q = OFF_W1Q + 288;          // 18432 (fp32 dequant w2 — unused now)
constexpr int OFF_W3Q = OFF_W2Q + 18432;        // 1024
constexpr int OFF_W4Q = OFF_W3Q + 1024;         // 2304
constexpr int OFF_W5Q = OFF_W4Q + 2304;         // 1024
constexpr int OFF_WLQ = OFF_W5Q + 1024;         // 640
constexpr int OFF_B1Q = OFF_WLQ + 640;          // 32
constexpr int OFF_B2Q = OFF_B1Q + 32;           // 64
constexpr int OFF_B3Q = OFF_B2Q + 64;           // 16
constexpr int OFF_B4Q = OFF_B3Q + 16;           // 16
constexpr int OFF_B5Q = OFF_B4Q + 16;           // 64
constexpr int OFF_BLQ = OFF_B5Q + 64;           // 10
constexpr int OFF_SKIP1 = 24576;                        // B*64    = 262144
constexpr int OFF_A2    = OFF_SKIP1 + BATCH * 64;       // B*64*64 = 16777216
constexpr int OFF_A1    = OFF_A2 + BATCH * 64 * 64;     // B*256*32 [pos][ic]
// after conv2, a1 region is dead -> reuse for skip2/a3/a4/a5
constexpr int OFF_SKIP2 = OFF_A1;                       // B*64*16 = 4194304
constexpr int OFF_A3    = OFF_SKIP2 + BATCH * 64 * 16;  // B*16*64 = 4194304
constexpr int OFF_A4    = OFF_A3 + BATCH * 16 * 64;     // B*16*16 = 1048576
constexpr int OFF_A5    = OFF_A4 + BATCH * 16 * 16;     // B*64*16 = 4194304
// w2 integer-level bf16 [64][288] lives after a1 (as shorts in this float slot)
constexpr size_t OFF_W2I = (size_t)OFF_A1 + (size_t)BATCH * 32 * 256;
constexpr size_t WS_FLOATS_NEEDED = OFF_W2I + 18432 + 64;

// ---------------- helpers ----------------
__device__ __forceinline__ float fq(float x, float scale, float maxv) {
    float q = rintf(x * scale);                 // round-half-even, same as jnp.round
    q = fminf(fmaxf(q, -maxv), maxv);
    return q / scale;
}

__device__ __forceinline__ float ld_act_scale(const unsigned* slot) {
    return 127.0f / __uint_as_float(*slot);
}

// exact bf16 bits for a float that is a small integer (|v| <= 255): low 16 bits are zero
__device__ __forceinline__ short int_to_bf16_bits(float v) {
    return (short)(__float_as_uint(v) >> 16);
}

__device__ __forceinline__ void block_max_atomic(float v, unsigned* dst, float* red) {
    int tid = threadIdx.x;
    red[tid] = v;
    __syncthreads();
    for (int s = 128; s > 0; s >>= 1) {
        if (tid < s) red[tid] = fmaxf(red[tid], red[tid + s]);
        __syncthreads();
    }
    if (tid == 0) atomicMax(dst, __float_as_uint(red[0]));
}

// ---------------- weight fake-quant (12 tensors, one block each) ----------------
struct WeightArgs {
    const float* src[12];
    float*       dst[12];
    int          n[12];
    float        maxv[12];
};

__global__ __launch_bounds__(256) void k_weights(WeightArgs a) {
    int t = blockIdx.x;
    const float* s = a.src[t];
    float* d = a.dst[t];
    int n = a.n[t];
    float maxv = a.maxv[t];
    __shared__ float red[256];
    int tid = threadIdx.x;
    float m = 0.f;
    for (int i = tid; i < n; i += 256) m = fmaxf(m, fabsf(s[i]));
    red[tid] = m;
    __syncthreads();
    for (int sft = 128; sft > 0; sft >>= 1) {
        if (tid < sft) red[tid] = fmaxf(red[tid], red[tid + sft]);
        __syncthreads();
    }
    float scale = maxv / red[0];
    for (int i = tid; i < n; i += 256) {
        float q = rintf(s[i] * scale);
        q = fminf(fmaxf(q, -maxv), maxv);
        d[i] = q / scale;
    }
}

// w2 raw [64][32][9] -> integer-level bf16 w2i[oc][t*32+ic]; also 1/sw2 to slot
__global__ __launch_bounds__(256) void k_prep_w2(const float* __restrict__ w2,
                                                 short* __restrict__ w2i,
                                                 float* __restrict__ inv_sw_slot) {
    __shared__ float red[256];
    int tid = threadIdx.x;
    float m = 0.f;
    for (int i = tid; i < 18432; i += 256) m = fmaxf(m, fabsf(w2[i]));
    red[tid] = m;
    __syncthreads();
    for (int s = 128; s > 0; s >>= 1) {
        if (tid < s) red[tid] = fmaxf(red[tid], red[tid + s]);
        __syncthreads();
    }
    float maxw = red[0];
    float sw = 127.f / maxw;
    if (tid == 0) *inv_sw_slot = maxw / 127.f;
    for (int i = tid; i < 18432; i += 256) {
        int oc = i / 288, r = i % 288, ic = r / 9, t = r % 9;
        float q = rintf(w2[i] * sw);
        q = fminf(fmaxf(q, -127.f), 127.f);
        w2i[oc * 288 + t * 32 + ic] = int_to_bf16_bits(q);
    }
}

// ---------------- global abs-max over x (float4-vectorized) ----------------
__global__ __launch_bounds__(256) void k_absmax(const float4* __restrict__ x, int n4,
                                                unsigned* out) {
    __shared__ float red[256];
    float m = 0.f;
    for (int i = blockIdx.x * 256 + threadIdx.x; i < n4; i += gridDim.x * 256) {
        float4 v = x[i];
        m = fmaxf(m, fmaxf(fmaxf(fabsf(v.x), fabsf(v.y)), fmaxf(fabsf(v.z), fabsf(v.w))));
    }
    block_max_atomic(m, out, red);
}

// ---------------- conv1: 1->32, 3x3, s2 p1, 32x32->16x16, clip; also skip1 ----------------
// a1 written TRANSPOSED: [img][256 pos][32 ic] so conv2 can vector-stage per position.
__global__ __launch_bounds__(256) void k_conv1(const float* __restrict__ x,
                                               const float* __restrict__ w1q,
                                               const float* __restrict__ b1q,
                                               const unsigned* xmax_bits,
                                               float* __restrict__ a1,
                                               float* __restrict__ skip1,
                                               unsigned* actmax) {
    __shared__ float tile[34 * 34];
    __shared__ float red[256];
    int b = blockIdx.x, tid = threadIdx.x;
    float sx = ld_act_scale(xmax_bits);
    for (int i = tid; i < 34 * 34; i += 256) tile[i] = 0.f;
    __syncthreads();
    const float* xi = x + b * 1024;
    for (int i = tid; i < 1024; i += 256) {
        int ih = i >> 5, iw = i & 31;
        tile[(ih + 1) * 34 + (iw + 1)] = fq(xi[i], sx, 127.f);
    }
    __syncthreads();
    if (tid < 64) {
        int soh = tid >> 3, sow = tid & 7;
        float m = -INFINITY;
        int h0 = soh * 4 - 2, w0 = sow * 4 - 2;
        for (int kh = 0; kh < 5; kh++) {
            int ih = h0 + kh;
            if (ih < 0 || ih >= 32) continue;
            for (int kw = 0; kw < 5; kw++) {
                int iw = w0 + kw;
                if (iw < 0 || iw >= 32) continue;
                m = fmaxf(m, xi[ih * 32 + iw]);
            }
        }
        skip1[b * 64 + tid] = fq(m, sx, 127.f);
    }
    int oh = tid >> 4, ow = tid & 15;
    float in[9];
#pragma unroll
    for (int kh = 0; kh < 3; kh++)
#pragma unroll
        for (int kw = 0; kw < 3; kw++)
            in[kh * 3 + kw] = tile[(oh * 2 + kh) * 34 + (ow * 2 + kw)];
    float lmax = 0.f;
    float vout[32];
#pragma unroll
    for (int oc = 0; oc < 32; oc++) {
        float acc = b1q[oc];
#pragma unroll
        for (int k = 0; k < 9; k++) acc += in[k] * w1q[oc * 9 + k];
        float v = fminf(fmaxf(acc, 0.f), 10.f);
        vout[oc] = v;
        lmax = fmaxf(lmax, v);
    }
    float4* o4 = (float4*)(a1 + (size_t)b * 8192 + tid * 32);
#pragma unroll
    for (int c = 0; c < 8; c++) o4[c] = *(float4*)(vout + c * 4);
    block_max_atomic(lmax, actmax, red);
}

// ---------------- conv2 via bf16 MFMA (exact integer arithmetic) ----------------
// Per image: D[64 pos][64 oc] = A[64][288] x W[288][64], K = 9 taps x 32 ic.
// A staged in LDS as integer-level bf16 tile [18][18][40] (halo zeros, 16B-aligned ic stride);
// W kept in registers (9 b-frags per wave, wave w owns oc 16w..16w+15).
#define C2_IMG 4
#define C2_S   40            // ic stride in shorts (80B, 16B aligned)
#define C2_ROW (18 * C2_S)   // tile row stride in shorts
#define C2_TILE (18 * C2_ROW)

__global__ __launch_bounds__(256) void k_conv2(const float* __restrict__ a1,
                                               const short* __restrict__ w2i,
                                               const float* __restrict__ b2q,
                                               const float* __restrict__ skip1,
                                               const unsigned* m1bits,
                                               const float* __restrict__ inv_sw2p,
                                               float* __restrict__ a2,
                                               unsigned* actmax) {
    __shared__ short tile[2][C2_TILE];
    __shared__ float red[256];
    int tid = threadIdx.x;
    int lane = tid & 63, wv = tid >> 6;
    float max1 = __uint_as_float(*m1bits);
    float s1 = 127.f / max1;
    float inv = (max1 / 127.f) * (*inv_sw2p);

    // zero both tiles once (halo must be 0; interior gets overwritten per image)
    for (int i = tid; i < 2 * C2_TILE; i += 256) ((short*)tile)[i] = 0;

    // per-wave weight fragments: b[t][lane] = W[t*32 + (lane>>4)*8 + j][oc], oc = wv*16 + (lane&15)
    int oc = wv * 16 + (lane & 15);
    bf16x8 bf[9];
#pragma unroll
    for (int t = 0; t < 9; t++)
        bf[t] = *(const bf16x8*)(w2i + oc * 288 + t * 32 + (lane >> 4) * 8);
    float bias = b2q[oc];

    int img0 = blockIdx.x * C2_IMG;
    // staging address pieces for this thread (position tid)
    int sih = (tid >> 4) + 1, siw = (tid & 15) + 1;
    short* sdst0 = &tile[0][sih * C2_ROW + siw * C2_S];
    short* sdst1 = &tile[1][sih * C2_ROW + siw * C2_S];
    // A-frag base (within a tile) for each mblk
    float lmax = 0.f;
    __syncthreads();   // zero-init visible

    // stage image 0 into buffer 0
    {
        const float4* src = (const float4*)(a1 + (size_t)img0 * 8192 + tid * 32);
#pragma unroll
        for (int c = 0; c < 8; c++) {
            float4 v = src[c];
            short4v o;
            o.x = int_to_bf16_bits(rintf(v.x * s1));
            o.y = int_to_bf16_bits(rintf(v.y * s1));
            o.z = int_to_bf16_bits(rintf(v.z * s1));
            o.w = int_to_bf16_bits(rintf(v.w * s1));
            *(short4v*)(sdst0 + c * 4) = o;
        }
    }
    __syncthreads();

    for (int li = 0; li < C2_IMG; li++) {
        int bb = li & 1;
        // stage next image into the other buffer (overlaps with compute below)
        if (li + 1 < C2_IMG) {
            const float4* src = (const float4*)(a1 + (size_t)(img0 + li + 1) * 8192 + tid * 32);
            short* sd = bb ? sdst0 : sdst1;
#pragma unroll
            for (int c = 0; c < 8; c++) {
                float4 v = src[c];
                short4v o;
                o.x = int_to_bf16_bits(rintf(v.x * s1));
                o.y = int_to_bf16_bits(rintf(v.y * s1));
                o.z = int_to_bf16_bits(rintf(v.z * s1));
                o.w = int_to_bf16_bits(rintf(v.w * s1));
                *(short4v*)(sd + c * 4) = o;
            }
        }
        // compute current image
        int img = img0 + li;
        const short* tb = tile[bb];
        const float* sk = skip1 + (size_t)img * 64;
        float* o = a2 + (size_t)img * 4096;
#pragma unroll
        for (int mb = 0; mb < 4; mb++) {
            int m = mb * 16 + (lane & 15);
            int oh = m >> 3, ow = m & 7;
            const short* abase = tb + (oh * 2) * C2_ROW + (ow * 2) * C2_S + (lane >> 4) * 8;
            f32x4 acc = {0.f, 0.f, 0.f, 0.f};
#pragma unroll
            for (int kh = 0; kh < 3; kh++)
#pragma unroll
                for (int kw = 0; kw < 3; kw++) {
                    bf16x8 a = *(const bf16x8*)(abase + kh * C2_ROW + kw * C2_S);
                    acc = __builtin_amdgcn_mfma_f32_16x16x32_bf16(a, bf[kh * 3 + kw], acc, 0, 0, 0);
                }
#pragma unroll
            for (int r = 0; r < 4; r++) {
                int pos = mb * 16 + (lane >> 4) * 4 + r;
                float v = acc[r] * inv + bias + sk[pos];
                v = fminf(fmaxf(v, 0.f), 10.f);
                o[oc * 64 + pos] = v;
                lmax = fmaxf(lmax, v);
            }
        }
        __syncthreads();
    }
    block_max_atomic(lmax, actmax, red);
}

// ---------------- conv3: 1x1, 64->16 on 8x8, clip; also skip2 = maxpool(fq(a2),3,2,1) ----------------
__global__ __launch_bounds__(256) void k_conv3(const float* __restrict__ a2,
                                               const float* __restrict__ w3q,
                                               const float* __restrict__ b3q,
                                               const unsigned* m2bits,
                                               float* __restrict__ a3,
                                               float* __restrict__ skip2,
                                               unsigned* actmax) {
    __shared__ float tin[64 * 64];
    __shared__ float red[256];
    int b = blockIdx.x, tid = threadIdx.x;
    float s2 = ld_act_scale(m2bits);
    const float* ai = a2 + (size_t)b * 4096;
    for (int i = tid; i < 4096; i += 256) tin[i] = fq(ai[i], s2, 127.f);
    __syncthreads();
    float* sko = skip2 + (size_t)b * 1024;
#pragma unroll
    for (int r = 0; r < 4; ++r) {
        int idx = tid * 4 + r;
        int c = idx >> 4, pp = idx & 15, soh = pp >> 2, sow = pp & 3;
        float m = -INFINITY;
        for (int kh = 0; kh < 3; kh++) {
            int ih = soh * 2 - 1 + kh;
            if (ih < 0 || ih >= 8) continue;
            for (int kw = 0; kw < 3; kw++) {
                int iw = sow * 2 - 1 + kw;
                if (iw < 0 || iw >= 8) continue;
                m = fmaxf(m, tin[c * 64 + ih * 8 + iw]);
            }
        }
        sko[idx] = m;
    }
    int p = tid & 63;
    int grp = __builtin_amdgcn_readfirstlane(tid >> 6);
    float acc[4];
#pragma unroll
    for (int j = 0; j < 4; ++j) acc[j] = b3q[grp * 4 + j];
    for (int ic = 0; ic < 64; ++ic) {
        float v = tin[ic * 64 + p];
#pragma unroll
        for (int j = 0; j < 4; ++j)
            acc[j] = fmaf(v, w3q[(grp * 4 + j) * 64 + ic], acc[j]);
    }
    float lmax = 0.f;
    float* o = a3 + (size_t)b * 1024;
#pragma unroll
    for (int j = 0; j < 4; ++j) {
        float v = fminf(fmaxf(acc[j], 0.f), 10.f);
        o[(grp * 4 + j) * 64 + p] = v;
        lmax = fmaxf(lmax, v);
    }
    block_max_atomic(lmax, actmax, red);
}

// ---------------- conv4: 3x3, s2 p1, 16->16, 8x8->4x4, clip ----------------
__global__ __launch_bounds__(256) void k_conv4(const float* __restrict__ a3,
                                               const float* __restrict__ w4q,
                                               const float* __restrict__ b4q,
                                               const unsigned* m3bits,
                                               float* __restrict__ a4,
                                               unsigned* actmax) {
    __shared__ float tile[16 * 10 * 10];
    __shared__ float red[256];
    int b = blockIdx.x, tid = threadIdx.x;
    float s3 = ld_act_scale(m3bits);
    for (int i = tid; i < 1600; i += 256) tile[i] = 0.f;
    __syncthreads();
    const float* ai = a3 + (size_t)b * 1024;
    for (int i = tid; i < 1024; i += 256) {
        int ic = i >> 6, p = i & 63, ih = p >> 3, iw = p & 7;
        tile[ic * 100 + (ih + 1) * 10 + (iw + 1)] = fq(ai[i], s3, 127.f);
    }
    __syncthreads();
    int oc = tid >> 4, p = tid & 15, oh = p >> 2, ow = p & 3;
    float acc = b4q[oc];
    const float* w = w4q + oc * 144;
    for (int ic = 0; ic < 16; ic++) {
        const float* tin = tile + ic * 100 + (oh * 2) * 10 + (ow * 2);
        const float* wc = w + ic * 9;
#pragma unroll
        for (int kh = 0; kh < 3; kh++)
#pragma unroll
            for (int kw = 0; kw < 3; kw++)
                acc += tin[kh * 10 + kw] * wc[kh * 3 + kw];
    }
    float v = fminf(fmaxf(acc, 0.f), 10.f);
    a4[(size_t)b * 256 + tid] = v;
    block_max_atomic(v, actmax, red);
}

// ---------------- conv5: 1x1, 16->64 on 4x4, +skip2, clip ----------------
__global__ __launch_bounds__(256) void k_conv5(const float* __restrict__ a4,
                                               const float* __restrict__ w5q,
                                               const float* __restrict__ b5q,
                                               const float* __restrict__ skip2,
                                               const unsigned* m4bits,
                                               float* __restrict__ a5,
                                               unsigned* actmax) {
    __shared__ float tin[256];
    __shared__ float red[256];
    int b = blockIdx.x, tid = threadIdx.x;
    float s4 = ld_act_scale(m4bits);
    const float* ai = a4 + (size_t)b * 256;
    tin[tid] = fq(ai[tid], s4, 127.f);
    __syncthreads();
    int p = tid & 15, ocb = tid >> 4;
    float lmax = 0.f;
    float* o = a5 + (size_t)b * 1024;
    for (int j = 0; j < 4; j++) {
        int oc = ocb * 4 + j;
        float acc = b5q[oc];
        const float* w = w5q + oc * 16;
#pragma unroll
        for (int ic = 0; ic < 16; ic++) acc += tin[ic * 16 + p] * w[ic];
        acc += skip2[(size_t)b * 1024 + oc * 16 + p];
        float v = fminf(fmaxf(acc, 0.f), 10.f);
        o[oc * 16 + p] = v;
        lmax = fmaxf(lmax, v);
    }
    block_max_atomic(lmax, actmax, red);
}

// ---------------- head: fq(a5) -> mean(4x4) -> linear ----------------
__global__ __launch_bounds__(64) void k_head(const float* __restrict__ a5,
                                             const unsigned* m5bits,
                                             const float* __restrict__ wlq,
                                             const float* __restrict__ blq,
                                             float* __restrict__ out) {
    __shared__ float h[64];
    int b = blockIdx.x, c = threadIdx.x;
    float s5 = ld_act_scale(m5bits);
    const float* ai = a5 + (size_t)b * 1024 + c * 16;
    float sum = 0.f;
#pragma unroll
    for (int p = 0; p < 16; p++) sum += fq(ai[p], s5, 127.f);
    h[c] = sum * (1.f / 16.f);
    __syncthreads();
    if (c < 10) {
        float acc = blq[c];
        const float* w = wlq + c * 64;
        for (int ic = 0; ic < 64; ic++) acc += h[ic] * w[ic];
        out[(size_t)b * 10 + c] = acc;
    }
}

// ---------------- launch ----------------
extern "C" void kernel_launch(void* const* d_in, const int* in_sizes, int n_in,
                              void* d_out, int out_size, void* d_ws, size_t ws_size,
                              hipStream_t stream) {
    const float* x  = (const float*)d_in[0];
    const float* w1 = (const float*)d_in[1];
    const float* b1 = (const float*)d_in[2];
    const float* w2 = (const float*)d_in[3];
    const float* b2 = (const float*)d_in[4];
    const float* w3 = (const float*)d_in[5];
    const float* b3 = (const float*)d_in[6];
    const float* w4 = (const float*)d_in[7];
    const float* b4 = (const float*)d_in[8];
    const float* w5 = (const float*)d_in[9];
    const float* b5 = (const float*)d_in[10];
    const float* wl = (const float*)d_in[11];
    const float* bl = (const float*)d_in[12];

    if (ws_size < WS_FLOATS_NEEDED * sizeof(float)) return;

    float* ws = (float*)d_ws;
    unsigned* slots = (unsigned*)d_ws;   // [0]=xmax, [1..5]=act maxes, [6]=inv_sw2 (float)
    short* w2i = (short*)(ws + OFF_W2I);

    hipMemsetAsync(d_ws, 0, 1024, stream);

    WeightArgs wa;
    const float* srcs[12] = {w1, w2, w3, w4, w5, wl, b1, b2, b3, b4, b5, bl};
    const int    ns[12]   = {288, 18432, 1024, 2304, 1024, 640, 32, 64, 16, 16, 64, 10};
    const int    offs[12] = {OFF_W1Q, OFF_W2Q, OFF_W3Q, OFF_W4Q, OFF_W5Q, OFF_WLQ,
                             OFF_B1Q, OFF_B2Q, OFF_B3Q, OFF_B4Q, OFF_B5Q, OFF_BLQ};
    const float  mv[12]   = {127.f, 127.f, 127.f, 127.f, 127.f, 127.f,
                             32767.f, 32767.f, 32767.f, 32767.f, 32767.f, 32767.f};
    for (int i = 0; i < 12; i++) {
        wa.src[i] = srcs[i];
        wa.dst[i] = ws + offs[i];
        wa.n[i] = ns[i];
        wa.maxv[i] = mv[i];
    }
    k_weights<<<12, 256, 0, stream>>>(wa);
    k_prep_w2<<<1, 256, 0, stream>>>(w2, w2i, ws + 6);

    k_absmax<<<512, 256, 0, stream>>>((const float4*)x, BATCH * 1024 / 4, slots + 0);
    k_conv1<<<BATCH, 256, 0, stream>>>(x, ws + OFF_W1Q, ws + OFF_B1Q, slots + 0,
                                       ws + OFF_A1, ws + OFF_SKIP1, slots + 1);
    k_conv2<<<BATCH / C2_IMG, 256, 0, stream>>>(ws + OFF_A1, w2i, ws + OFF_B2Q,
                                                ws + OFF_SKIP1, slots + 1, ws + 6,
                                                ws + OFF_A2, slots + 2);
    k_conv3<<<BATCH, 256, 0, stream>>>(ws + OFF_A2, ws + OFF_W3Q, ws + OFF_B3Q, slots + 2,
                                       ws + OFF_A3, ws + OFF_SKIP2, slots + 3);
    k_conv4<<<BATCH, 256, 0, stream>>>(ws + OFF_A3, ws + OFF_W4Q, ws + OFF_B4Q, slots + 3,
                                       ws + OFF_A4, slots + 4);
    k_conv5<<<BATCH, 256, 0, stream>>>(ws + OFF_A4, ws + OFF_W5Q, ws + OFF_B5Q,
                                       ws + OFF_SKIP2, slots + 4, ws + OFF_A5, slots + 5);
    k_head<<<BATCH, 64, 0, stream>>>(ws + OFF_A5, slots + 5, ws + OFF_WLQ, ws + OFF_BLQ,
                                     (float*)d_out);
}

// Round 5
// 405.445 us; speedup vs baseline: 3.2530x; 1.0246x over previous
//
#include <hip/hip_runtime.h>

#define BATCH 4096

typedef __attribute__((ext_vector_type(8))) short bf16x8;
typedef __attribute__((ext_vector_type(4))) float f32x4;
typedef __attribute__((ext_vector_type(4))) short short4v;

// ---------------- ws layout (in floats) ----------------
// slots: [0]=xmax bits, [1..5]=act max bits, [6]=inv_sw2, [7]=inv_sw3
constexpr int OFF_W1Q = 256;                    // 288
constexpr int OFF_W2Q = OFF_W1Q + 288;          // 18432 (fp32, unused by conv2 path)
constexpr int OFF_W3Q = OFF_W2Q + 18432;        // 1024  (fp32, unused by conv3 path)
constexpr int OFF_W4Q = OFF_W3Q + 1024;         // 2304
constexpr int OFF_W5Q = OFF_W4Q + 2304;         // 1024
constexpr int OFF_WLQ = OFF_W5Q + 1024;         // 640
constexpr int OFF_B1Q = OFF_WLQ + 640;          // 32
constexpr int OFF_B2Q = OFF_B1Q + 32;           // 64
constexpr int OFF_B3Q = OFF_B2Q + 64;           // 16
constexpr int OFF_B4Q = OFF_B3Q + 16;           // 16
constexpr int OFF_B5Q = OFF_B4Q + 16;           // 64
constexpr int OFF_BLQ = OFF_B5Q + 64;           // 10
constexpr int OFF_W2I = 24576;                  // 18432 shorts = 9216 floats
constexpr int OFF_W3I = OFF_W2I + 9216;         // 1024 shorts = 512 floats
constexpr int OFF_SKIP2 = 40960;                        // B*1024 = 4194304
constexpr int OFF_A3    = OFF_SKIP2 + BATCH * 1024;     // B*1024 = 4194304
constexpr int OFF_A4    = OFF_A3 + BATCH * 1024;        // B*256  = 1048576
constexpr int OFF_A5    = OFF_A4 + BATCH * 256;         // B*1024 = 4194304
constexpr size_t WS_FLOATS_NEEDED = (size_t)OFF_A5 + (size_t)BATCH * 1024;

// ---------------- helpers ----------------
__device__ __forceinline__ float fq(float x, float scale, float maxv) {
    float q = rintf(x * scale);                 // round-half-even == jnp.round
    q = fminf(fmaxf(q, -maxv), maxv);
    return q / scale;
}

__device__ __forceinline__ float ld_act_scale(const unsigned* slot) {
    return 127.0f / __uint_as_float(*slot);
}

// exact bf16 bits for a float that is a small nonneg integer (|v| <= 255)
__device__ __forceinline__ short int_to_bf16_bits(float v) {
    return (short)(__float_as_uint(v) >> 16);
}

__device__ __forceinline__ float bf16_bits_to_float(short b) {
    return __uint_as_float(((unsigned)(unsigned short)b) << 16);
}

__device__ __forceinline__ void block_max_atomic(float v, unsigned* dst, float* red) {
    int tid = threadIdx.x;
    red[tid] = v;
    __syncthreads();
    for (int s = 128; s > 0; s >>= 1) {
        if (tid < s) red[tid] = fmaxf(red[tid], red[tid + s]);
        __syncthreads();
    }
    if (tid == 0) atomicMax(dst, __float_as_uint(red[0]));
}

// shared conv1 arithmetic: one code path => bitwise identical across kernels
__device__ __forceinline__ void stage_x_tile(const float* xi, float sx, float* xt, int tid) {
    for (int i = tid; i < 1024; i += 256) {
        int ih = i >> 5, iw = i & 31;
        xt[(ih + 1) * 34 + (iw + 1)] = fq(xi[i], sx, 127.f);
    }
}

__device__ __forceinline__ void conv1_pos(const float* xt, const float* w1q, const float* b1q,
                                          int tid, float out[32]) {
    int oh = tid >> 4, ow = tid & 15;
    float in[9];
#pragma unroll
    for (int kh = 0; kh < 3; kh++)
#pragma unroll
        for (int kw = 0; kw < 3; kw++)
            in[kh * 3 + kw] = xt[(oh * 2 + kh) * 34 + (ow * 2 + kw)];
#pragma unroll
    for (int oc = 0; oc < 32; oc++) {
        float acc = b1q[oc];
#pragma unroll
        for (int k = 0; k < 9; k++) acc = fmaf(in[k], w1q[oc * 9 + k], acc);
        out[oc] = fminf(fmaxf(acc, 0.f), 10.f);
    }
}

// ---------------- weight fake-quant (12 tensors, one block each) ----------------
struct WeightArgs {
    const float* src[12];
    float*       dst[12];
    int          n[12];
    float        maxv[12];
};

__global__ __launch_bounds__(256) void k_weights(WeightArgs a) {
    int t = blockIdx.x;
    const float* s = a.src[t];
    float* d = a.dst[t];
    int n = a.n[t];
    float maxv = a.maxv[t];
    __shared__ float red[256];
    int tid = threadIdx.x;
    float m = 0.f;
    for (int i = tid; i < n; i += 256) m = fmaxf(m, fabsf(s[i]));
    red[tid] = m;
    __syncthreads();
    for (int sft = 128; sft > 0; sft >>= 1) {
        if (tid < sft) red[tid] = fmaxf(red[tid], red[tid + sft]);
        __syncthreads();
    }
    float scale = maxv / red[0];
    for (int i = tid; i < n; i += 256) {
        float q = rintf(s[i] * scale);
        q = fminf(fmaxf(q, -maxv), maxv);
        d[i] = q / scale;
    }
}

// w2 raw [64][32][9] -> integer-level bf16 w2i[oc][t*32+ic]; inv scale to slot
__global__ __launch_bounds__(256) void k_prep_w2(const float* __restrict__ w2,
                                                 short* __restrict__ w2i,
                                                 float* __restrict__ inv_sw_slot) {
    __shared__ float red[256];
    int tid = threadIdx.x;
    float m = 0.f;
    for (int i = tid; i < 18432; i += 256) m = fmaxf(m, fabsf(w2[i]));
    red[tid] = m;
    __syncthreads();
    for (int s = 128; s > 0; s >>= 1) {
        if (tid < s) red[tid] = fmaxf(red[tid], red[tid + s]);
        __syncthreads();
    }
    float maxw = red[0];
    float sw = 127.f / maxw;
    if (tid == 0) *inv_sw_slot = maxw / 127.f;
    for (int i = tid; i < 18432; i += 256) {
        int oc = i / 288, r = i % 288, ic = r / 9, t = r % 9;
        float q = rintf(w2[i] * sw);
        q = fminf(fmaxf(q, -127.f), 127.f);
        w2i[oc * 288 + t * 32 + ic] = int_to_bf16_bits(q);
    }
}

// w3 raw [16][64] -> integer-level bf16 w3i[oc][ic]; inv scale to slot
__global__ __launch_bounds__(256) void k_prep_w3(const float* __restrict__ w3,
                                                 short* __restrict__ w3i,
                                                 float* __restrict__ inv_sw_slot) {
    __shared__ float red[256];
    int tid = threadIdx.x;
    float m = 0.f;
    for (int i = tid; i < 1024; i += 256) m = fmaxf(m, fabsf(w3[i]));
    red[tid] = m;
    __syncthreads();
    for (int s = 128; s > 0; s >>= 1) {
        if (tid < s) red[tid] = fmaxf(red[tid], red[tid + s]);
        __syncthreads();
    }
    float maxw = red[0];
    float sw = 127.f / maxw;
    if (tid == 0) *inv_sw_slot = maxw / 127.f;
    for (int i = tid; i < 1024; i += 256) {
        float q = rintf(w3[i] * sw);
        q = fminf(fmaxf(q, -127.f), 127.f);
        w3i[i] = int_to_bf16_bits(q);
    }
}

// ---------------- global abs-max over x ----------------
__global__ __launch_bounds__(256) void k_absmax(const float4* __restrict__ x, int n4,
                                                unsigned* out) {
    __shared__ float red[256];
    float m = 0.f;
    for (int i = blockIdx.x * 256 + threadIdx.x; i < n4; i += gridDim.x * 256) {
        float4 v = x[i];
        m = fmaxf(m, fmaxf(fmaxf(fabsf(v.x), fabsf(v.y)), fmaxf(fabsf(v.z), fabsf(v.w))));
    }
    block_max_atomic(m, out, red);
}

// ---------------- conv1 max-only pass: m1, no stores ----------------
__global__ __launch_bounds__(256) void k_c1max(const float* __restrict__ x,
                                               const float* __restrict__ w1q,
                                               const float* __restrict__ b1q,
                                               const unsigned* xmax_bits,
                                               unsigned* actmax) {
    __shared__ float xt[34 * 34];
    __shared__ float red[256];
    int tid = threadIdx.x;
    float sx = ld_act_scale(xmax_bits);
    for (int i = tid; i < 34 * 34; i += 256) xt[i] = 0.f;
    __syncthreads();
    stage_x_tile(x + (size_t)blockIdx.x * 1024, sx, xt, tid);
    __syncthreads();
    float o1[32];
    conv1_pos(xt, w1q, b1q, tid, o1);
    float lmax = 0.f;
#pragma unroll
    for (int c = 0; c < 32; c++) lmax = fmaxf(lmax, o1[c]);
    block_max_atomic(lmax, actmax, red);
}

// ---------------- fused conv1+conv2 (+conv3 when FUSE3) ----------------
// Per block: 4 images sequential. a1 quantized straight into bf16 LDS tile with m1;
// conv2 = 36 exact-integer MFMAs; FUSE3: a2 quantized to int-bf16 LDS, conv3 = 2 MFMAs,
// skip2 pooled from quantized a2. Activations a1/a2/skip1 never touch HBM.
#define C12_IMG 4
#define A1_S   40             // ic stride in shorts (80B, 16B aligned)
#define A1_ROW (18 * A1_S)

template<bool FUSE3>
__global__ __launch_bounds__(256) void k_c12(const float* __restrict__ x,
                                             const float* __restrict__ w1q,
                                             const float* __restrict__ b1q,
                                             const short* __restrict__ w2i,
                                             const float* __restrict__ b2q,
                                             const unsigned* xmax_bits,
                                             const unsigned* m1bits,
                                             const float* __restrict__ inv_sw2p,
                                             const unsigned* m2bits,
                                             const short* __restrict__ w3i,
                                             const float* __restrict__ b3q,
                                             const float* __restrict__ inv_sw3p,
                                             float* __restrict__ a3,
                                             float* __restrict__ skip2,
                                             unsigned* outmax) {
    __shared__ float xt[34 * 34];
    __shared__ short a1t[18 * A1_ROW];
    __shared__ short a2q[64 * 64];
    __shared__ float sk1[64];
    __shared__ float red[256];

    int tid = threadIdx.x;
    int lane = tid & 63, wv = tid >> 6;
    float sx = ld_act_scale(xmax_bits);
    float m1 = __uint_as_float(*m1bits);
    float s1 = 127.f / m1;
    float inv2 = (m1 / 127.f) * (*inv_sw2p);
    float s2 = 0.f, invs2 = 0.f, inv3 = 0.f;
    if (FUSE3) {
        float m2 = __uint_as_float(*m2bits);
        s2 = 127.f / m2;
        invs2 = m2 / 127.f;
        inv3 = invs2 * (*inv_sw3p);
    }

    // zero halos once (interior overwritten per image)
    for (int i = tid; i < 34 * 34; i += 256) xt[i] = 0.f;
    for (int i = tid; i < 18 * A1_ROW / 2; i += 256) ((int*)a1t)[i] = 0;

    // per-wave conv2 weight fragments: wave wv owns oc = wv*16 + (lane&15)
    int oc2 = wv * 16 + (lane & 15);
    bf16x8 bw2[9];
#pragma unroll
    for (int t = 0; t < 9; t++)
        bw2[t] = *(const bf16x8*)(w2i + oc2 * 288 + t * 32 + (lane >> 4) * 8);
    float bias2 = b2q[oc2];

    bf16x8 bw3[2];
    float bias3 = 0.f;
    if (FUSE3) {
#pragma unroll
        for (int t = 0; t < 2; t++)
            bw3[t] = *(const bf16x8*)(w3i + (lane & 15) * 64 + t * 32 + (lane >> 4) * 8);
        bias3 = b3q[lane & 15];
    }

    short* a1dst = a1t + ((tid >> 4) + 1) * A1_ROW + ((tid & 15) + 1) * A1_S;
    float lmax = 0.f;

    for (int li = 0; li < C12_IMG; li++) {
        int img = blockIdx.x * C12_IMG + li;
        const float* xi = x + (size_t)img * 1024;
        __syncthreads();                       // prior image fully consumed
        stage_x_tile(xi, sx, xt, tid);
        __syncthreads();
        // conv1 for this thread's position; quantize to integer-level bf16
        float o1[32];
        conv1_pos(xt, w1q, b1q, tid, o1);
#pragma unroll
        for (int c = 0; c < 8; c++) {
            short4v v;
            v.x = int_to_bf16_bits(rintf(o1[c * 4 + 0] * s1));
            v.y = int_to_bf16_bits(rintf(o1[c * 4 + 1] * s1));
            v.z = int_to_bf16_bits(rintf(o1[c * 4 + 2] * s1));
            v.w = int_to_bf16_bits(rintf(o1[c * 4 + 3] * s1));
            *(short4v*)(a1dst + c * 4) = v;
        }
        // skip1 = pool(fq(x),5,4,2) from the fq'd x tile (monotone)
        if (tid < 64) {
            int soh = tid >> 3, sow = tid & 7;
            float m = -INFINITY;
            int h0 = soh * 4 - 2, w0 = sow * 4 - 2;
            for (int kh = 0; kh < 5; kh++) {
                int ih = h0 + kh;
                if (ih < 0 || ih >= 32) continue;
                for (int kw = 0; kw < 5; kw++) {
                    int iw = w0 + kw;
                    if (iw < 0 || iw >= 32) continue;
                    m = fmaxf(m, xt[(ih + 1) * 34 + (iw + 1)]);
                }
            }
            sk1[tid] = m;
        }
        __syncthreads();
        // conv2: 4 m-tiles x 9 taps of 16x16x32 bf16 MFMA (exact integer math)
#pragma unroll
        for (int mb = 0; mb < 4; mb++) {
            int m = mb * 16 + (lane & 15);
            int oh = m >> 3, ow = m & 7;
            const short* abase = a1t + (oh * 2) * A1_ROW + (ow * 2) * A1_S + (lane >> 4) * 8;
            f32x4 acc = {0.f, 0.f, 0.f, 0.f};
#pragma unroll
            for (int kh = 0; kh < 3; kh++)
#pragma unroll
                for (int kw = 0; kw < 3; kw++) {
                    bf16x8 a = *(const bf16x8*)(abase + kh * A1_ROW + kw * A1_S);
                    acc = __builtin_amdgcn_mfma_f32_16x16x32_bf16(a, bw2[kh * 3 + kw], acc, 0, 0, 0);
                }
#pragma unroll
            for (int r = 0; r < 4; r++) {
                int pos = mb * 16 + (lane >> 4) * 4 + r;
                float v = acc[r] * inv2 + bias2 + sk1[pos];
                v = fminf(fmaxf(v, 0.f), 10.f);
                if (FUSE3) {
                    float q = fminf(rintf(v * s2), 127.f);
                    a2q[pos * 64 + oc2] = int_to_bf16_bits(q);
                } else {
                    lmax = fmaxf(lmax, v);
                }
            }
        }
        if (FUSE3) {
            __syncthreads();                   // a2q complete
            // conv3: wave wv owns m-tile wv; N=16 oc, K=64 -> 2 MFMAs
            const short* abase = a2q + (wv * 16 + (lane & 15)) * 64 + (lane >> 4) * 8;
            f32x4 acc = {0.f, 0.f, 0.f, 0.f};
#pragma unroll
            for (int t = 0; t < 2; t++) {
                bf16x8 a = *(const bf16x8*)(abase + t * 32);
                acc = __builtin_amdgcn_mfma_f32_16x16x32_bf16(a, bw3[t], acc, 0, 0, 0);
            }
            float* a3o = a3 + (size_t)img * 1024;
#pragma unroll
            for (int r = 0; r < 4; r++) {
                int pos = wv * 16 + (lane >> 4) * 4 + r;
                float v = acc[r] * inv3 + bias3;
                v = fminf(fmaxf(v, 0.f), 10.f);
                a3o[(lane & 15) * 64 + pos] = v;
                lmax = fmaxf(lmax, v);
            }
            // skip2 = pool(fq(a2),3,2,1): max of integer q then scale
            float* sko = skip2 + (size_t)img * 1024;
#pragma unroll
            for (int r = 0; r < 4; ++r) {
                int idx = tid * 4 + r;
                int c = idx >> 4, pp = idx & 15, soh = pp >> 2, sow = pp & 3;
                float m = -INFINITY;
                for (int kh = 0; kh < 3; kh++) {
                    int ih = soh * 2 - 1 + kh;
                    if (ih < 0 || ih >= 8) continue;
                    for (int kw = 0; kw < 3; kw++) {
                        int iw = sow * 2 - 1 + kw;
                        if (iw < 0 || iw >= 8) continue;
                        m = fmaxf(m, bf16_bits_to_float(a2q[(ih * 8 + iw) * 64 + c]));
                    }
                }
                sko[idx] = m * invs2;
            }
        }
    }
    block_max_atomic(lmax, outmax, red);
}

// ---------------- conv4: 3x3, s2 p1, 16->16, 8x8->4x4, clip ----------------
__global__ __launch_bounds__(256) void k_conv4(const float* __restrict__ a3,
                                               const float* __restrict__ w4q,
                                               const float* __restrict__ b4q,
                                               const unsigned* m3bits,
                                               float* __restrict__ a4,
                                               unsigned* actmax) {
    __shared__ float tile[16 * 10 * 10];
    __shared__ float red[256];
    int b = blockIdx.x, tid = threadIdx.x;
    float s3 = ld_act_scale(m3bits);
    for (int i = tid; i < 1600; i += 256) tile[i] = 0.f;
    __syncthreads();
    const float* ai = a3 + (size_t)b * 1024;
    for (int i = tid; i < 1024; i += 256) {
        int ic = i >> 6, p = i & 63, ih = p >> 3, iw = p & 7;
        tile[ic * 100 + (ih + 1) * 10 + (iw + 1)] = fq(ai[i], s3, 127.f);
    }
    __syncthreads();
    int oc = tid >> 4, p = tid & 15, oh = p >> 2, ow = p & 3;
    float acc = b4q[oc];
    const float* w = w4q + oc * 144;
    for (int ic = 0; ic < 16; ic++) {
        const float* tin = tile + ic * 100 + (oh * 2) * 10 + (ow * 2);
        const float* wc = w + ic * 9;
#pragma unroll
        for (int kh = 0; kh < 3; kh++)
#pragma unroll
            for (int kw = 0; kw < 3; kw++)
                acc += tin[kh * 10 + kw] * wc[kh * 3 + kw];
    }
    float v = fminf(fmaxf(acc, 0.f), 10.f);
    a4[(size_t)b * 256 + tid] = v;
    block_max_atomic(v, actmax, red);
}

// ---------------- conv5: 1x1, 16->64 on 4x4, +skip2, clip ----------------
__global__ __launch_bounds__(256) void k_conv5(const float* __restrict__ a4,
                                               const float* __restrict__ w5q,
                                               const float* __restrict__ b5q,
                                               const float* __restrict__ skip2,
                                               const unsigned* m4bits,
                                               float* __restrict__ a5,
                                               unsigned* actmax) {
    __shared__ float tin[256];
    __shared__ float red[256];
    int b = blockIdx.x, tid = threadIdx.x;
    float s4 = ld_act_scale(m4bits);
    const float* ai = a4 + (size_t)b * 256;
    tin[tid] = fq(ai[tid], s4, 127.f);
    __syncthreads();
    int p = tid & 15, ocb = tid >> 4;
    float lmax = 0.f;
    float* o = a5 + (size_t)b * 1024;
    for (int j = 0; j < 4; j++) {
        int oc = ocb * 4 + j;
        float acc = b5q[oc];
        const float* w = w5q + oc * 16;
#pragma unroll
        for (int ic = 0; ic < 16; ic++) acc += tin[ic * 16 + p] * w[ic];
        acc += skip2[(size_t)b * 1024 + oc * 16 + p];
        float v = fminf(fmaxf(acc, 0.f), 10.f);
        o[oc * 16 + p] = v;
        lmax = fmaxf(lmax, v);
    }
    block_max_atomic(lmax, actmax, red);
}

// ---------------- head: fq(a5) -> mean(4x4) -> linear ----------------
__global__ __launch_bounds__(64) void k_head(const float* __restrict__ a5,
                                             const unsigned* m5bits,
                                             const float* __restrict__ wlq,
                                             const float* __restrict__ blq,
                                             float* __restrict__ out) {
    __shared__ float h[64];
    int b = blockIdx.x, c = threadIdx.x;
    float s5 = ld_act_scale(m5bits);
    const float* ai = a5 + (size_t)b * 1024 + c * 16;
    float sum = 0.f;
#pragma unroll
    for (int p = 0; p < 16; p++) sum += fq(ai[p], s5, 127.f);
    h[c] = sum * (1.f / 16.f);
    __syncthreads();
    if (c < 10) {
        float acc = blq[c];
        const float* w = wlq + c * 64;
        for (int ic = 0; ic < 64; ic++) acc += h[ic] * w[ic];
        out[(size_t)b * 10 + c] = acc;
    }
}

// ---------------- launch ----------------
extern "C" void kernel_launch(void* const* d_in, const int* in_sizes, int n_in,
                              void* d_out, int out_size, void* d_ws, size_t ws_size,
                              hipStream_t stream) {
    const float* x  = (const float*)d_in[0];
    const float* w1 = (const float*)d_in[1];
    const float* b1 = (const float*)d_in[2];
    const float* w2 = (const float*)d_in[3];
    const float* b2 = (const float*)d_in[4];
    const float* w3 = (const float*)d_in[5];
    const float* b3 = (const float*)d_in[6];
    const float* w4 = (const float*)d_in[7];
    const float* b4 = (const float*)d_in[8];
    const float* w5 = (const float*)d_in[9];
    const float* b5 = (const float*)d_in[10];
    const float* wl = (const float*)d_in[11];
    const float* bl = (const float*)d_in[12];

    if (ws_size < WS_FLOATS_NEEDED * sizeof(float)) return;

    float* ws = (float*)d_ws;
    unsigned* slots = (unsigned*)d_ws;
    short* w2i = (short*)(ws + OFF_W2I);
    short* w3i = (short*)(ws + OFF_W3I);

    hipMemsetAsync(d_ws, 0, 1024, stream);

    WeightArgs wa;
    const float* srcs[12] = {w1, w2, w3, w4, w5, wl, b1, b2, b3, b4, b5, bl};
    const int    ns[12]   = {288, 18432, 1024, 2304, 1024, 640, 32, 64, 16, 16, 64, 10};
    const int    offs[12] = {OFF_W1Q, OFF_W2Q, OFF_W3Q, OFF_W4Q, OFF_W5Q, OFF_WLQ,
                             OFF_B1Q, OFF_B2Q, OFF_B3Q, OFF_B4Q, OFF_B5Q, OFF_BLQ};
    const float  mv[12]   = {127.f, 127.f, 127.f, 127.f, 127.f, 127.f,
                             32767.f, 32767.f, 32767.f, 32767.f, 32767.f, 32767.f};
    for (int i = 0; i < 12; i++) {
        wa.src[i] = srcs[i];
        wa.dst[i] = ws + offs[i];
        wa.n[i] = ns[i];
        wa.maxv[i] = mv[i];
    }
    k_weights<<<12, 256, 0, stream>>>(wa);
    k_prep_w2<<<1, 256, 0, stream>>>(w2, w2i, ws + 6);
    k_prep_w3<<<1, 256, 0, stream>>>(w3, w3i, ws + 7);

    k_absmax<<<512, 256, 0, stream>>>((const float4*)x, BATCH * 1024 / 4, slots + 0);
    k_c1max<<<BATCH, 256, 0, stream>>>(x, ws + OFF_W1Q, ws + OFF_B1Q, slots + 0, slots + 1);
    k_c12<false><<<BATCH / C12_IMG, 256, 0, stream>>>(
        x, ws + OFF_W1Q, ws + OFF_B1Q, w2i, ws + OFF_B2Q, slots + 0, slots + 1, ws + 6,
        slots + 2, w3i, ws + OFF_B3Q, ws + 7, nullptr, nullptr, slots + 2);
    k_c12<true><<<BATCH / C12_IMG, 256, 0, stream>>>(
        x, ws + OFF_W1Q, ws + OFF_B1Q, w2i, ws + OFF_B2Q, slots + 0, slots + 1, ws + 6,
        slots + 2, w3i, ws + OFF_B3Q, ws + 7, ws + OFF_A3, ws + OFF_SKIP2, slots + 3);
    k_conv4<<<BATCH, 256, 0, stream>>>(ws + OFF_A3, ws + OFF_W4Q, ws + OFF_B4Q, slots + 3,
                                       ws + OFF_A4, slots + 4);
    k_conv5<<<BATCH, 256, 0, stream>>>(ws + OFF_A4, ws + OFF_W5Q, ws + OFF_B5Q,
                                       ws + OFF_SKIP2, slots + 4, ws + OFF_A5, slots + 5);
    k_head<<<BATCH, 64, 0, stream>>>(ws + OFF_A5, slots + 5, ws + OFF_WLQ, ws + OFF_BLQ,
                                     (float*)d_out);
}